// Round 1
// baseline (7765.189 us; speedup 1.0000x reference)
//
#include <hip/hip_runtime.h>
#include <stdint.h>

typedef unsigned short u16;
typedef __bf16 bf16x8 __attribute__((ext_vector_type(8)));
typedef float  f32x4  __attribute__((ext_vector_type(4)));

#define GPTR(p) ((const __attribute__((address_space(1))) void*)(p))
#define LPTR(p) ((__attribute__((address_space(3))) void*)(p))

__device__ __forceinline__ u16 f2bf(float f) {
  uint32_t u = __float_as_uint(f);
  u += 0x7FFFu + ((u >> 16) & 1u);
  return (u16)(u >> 16);
}
__device__ __forceinline__ float bf2f(u16 h) {
  return __uint_as_float(((uint32_t)h) << 16);
}
__device__ __forceinline__ float sigf(float x) { return 1.0f / (1.0f + __expf(-x)); }
__device__ __forceinline__ float tanhf_(float x) { return 1.0f - 2.0f / (__expf(2.0f * x) + 1.0f); }

// ---------------- embedding gather: x1[b*512+t][1024] = bf16(w_emb[seq]) ----------------
__global__ void k_emb(const int* __restrict__ seq, const float* __restrict__ wemb,
                      u16* __restrict__ x1) {
  const int row = blockIdx.x;          // 0..16383
  const int tok = seq[row];
  float4 v = ((const float4*)(wemb + (size_t)tok * 1024))[threadIdx.x];
  uint32_t lo = (uint32_t)f2bf(v.x) | ((uint32_t)f2bf(v.y) << 16);
  uint32_t hi = (uint32_t)f2bf(v.z) | ((uint32_t)f2bf(v.w) << 16);
  *(uint2*)(x1 + (size_t)row * 1024 + threadIdx.x * 4) = make_uint2(lo, hi);
}

// ---------------- marker index per row ----------------
__global__ void k_idx(const int* __restrict__ seq, int* __restrict__ idxb) {
  const int tid = threadIdx.x;         // 256
  const int b = tid >> 3, part = tid & 7;
  for (int t = part * 64; t < part * 64 + 64; ++t)
    if (seq[b * 512 + t] == 50000) idxb[b] = t;
}

// ---------------- cast 4096x1024 f32 -> bf16 ----------------
__global__ void k_cast(const float* __restrict__ src, u16* __restrict__ dst) {
  const int i = blockIdx.x * 256 + threadIdx.x;    // < 1048576 groups of 4
  float4 v = ((const float4*)src)[i];
  uint32_t lo = (uint32_t)f2bf(v.x) | ((uint32_t)f2bf(v.y) << 16);
  uint32_t hi = (uint32_t)f2bf(v.z) | ((uint32_t)f2bf(v.w) << 16);
  *(uint2*)(dst + (size_t)i * 4) = make_uint2(lo, hi);
}

// ---------------- GEMM: gx[d][t][b][col] = X[m=b*512+t][k]*W[n][k] + bias[n] ----------------
__global__ __launch_bounds__(256) void k_gemm(
    const u16* __restrict__ X, const u16* __restrict__ W,
    const float* __restrict__ bias, u16* __restrict__ gx)
{
  __shared__ u16 As[128][32];
  __shared__ u16 Bs[128][32];
  const int tid = threadIdx.x;
  const int lane = tid & 63;
  const int wv = tid >> 6;
  const int wm = wv >> 1, wn = wv & 1;
  const int bm = blockIdx.x, bn = blockIdx.y;
  const int srow = tid >> 2;
  const int scg = (tid & 3) * 8;
  const u16* Xb = X + (size_t)bm * 128 * 1024;
  const u16* Wb = W + (size_t)bn * 128 * 1024;
  f32x4 acc[4][4] = {};
  for (int k0 = 0; k0 < 1024; k0 += 32) {
    __builtin_amdgcn_global_load_lds(GPTR(Xb + (size_t)srow * 1024 + k0 + scg),       LPTR(&As[srow][scg]),       16, 0, 0);
    __builtin_amdgcn_global_load_lds(GPTR(Xb + (size_t)(srow + 64) * 1024 + k0 + scg), LPTR(&As[srow + 64][scg]), 16, 0, 0);
    __builtin_amdgcn_global_load_lds(GPTR(Wb + (size_t)srow * 1024 + k0 + scg),       LPTR(&Bs[srow][scg]),       16, 0, 0);
    __builtin_amdgcn_global_load_lds(GPTR(Wb + (size_t)(srow + 64) * 1024 + k0 + scg), LPTR(&Bs[srow + 64][scg]), 16, 0, 0);
    __syncthreads();
    const int kg = (lane >> 4) * 8;
    bf16x8 a4[4], b4[4];
    #pragma unroll
    for (int mt = 0; mt < 4; ++mt) a4[mt] = *(const bf16x8*)&As[wm * 64 + mt * 16 + (lane & 15)][kg];
    #pragma unroll
    for (int nt = 0; nt < 4; ++nt) b4[nt] = *(const bf16x8*)&Bs[wn * 64 + nt * 16 + (lane & 15)][kg];
    #pragma unroll
    for (int mt = 0; mt < 4; ++mt)
      #pragma unroll
      for (int nt = 0; nt < 4; ++nt)
        acc[mt][nt] = __builtin_amdgcn_mfma_f32_16x16x32_bf16(a4[mt], b4[nt], acc[mt][nt], 0, 0, 0);
    __syncthreads();
  }
  #pragma unroll
  for (int mt = 0; mt < 4; ++mt) {
    const int mbase = bm * 128 + wm * 64 + mt * 16 + ((lane >> 4) << 2);
    #pragma unroll
    for (int nt = 0; nt < 4; ++nt) {
      const int n = bn * 128 + wn * 64 + nt * 16 + (lane & 15);
      const float bi = bias[n];
      const int d = n >> 11, col = n & 2047;
      #pragma unroll
      for (int r = 0; r < 4; ++r) {
        const int mm = mbase + r;
        const int b = mm >> 9, t = mm & 511;
        gx[((size_t)(d * 512 + t) * 32 + b) * 2048 + col] = f2bf(acc[mt][nt][r] + bi);
      }
    }
  }
}

// ---------------- persistent bidirectional recurrence for one layer ----------------
// grid = 64 blocks: dir = bid>>5, chunk db = bid&31 owns h-cols [db*16, db*16+16)
// weights (64 gate rows x 512) live in registers; per-step device barrier per direction.
__global__ __launch_bounds__(256, 1) void k_rec(
    const u16* __restrict__ gx, const float* __restrict__ whh,
    u16* __restrict__ xout, u16* hbuf, unsigned* ctrbase)
{
  const int bid = blockIdx.x;
  const int dir = bid >> 5;
  const int db = bid & 31;
  const int j0 = db * 16;
  const int tid = threadIdx.x;
  const int lane = tid & 63;
  const int wv = tid >> 6;
  const int mh = wv >> 1, nh = wv & 1;
  unsigned* ctr = ctrbase + dir * 32;

  __shared__ float G[32][68];   // padded to break bank conflicts

  // ---- Whh chunk -> registers (bf16 fragments). B-frag: lane holds W[n][k0..k0+8)
  bf16x8 bw[2][16];
  {
    const int r = lane & 15;
    const int kg = (lane >> 4) * 8;
    #pragma unroll
    for (int nt = 0; nt < 2; ++nt) {
      const int q = nh * 2 + nt;   // gate: 0=i 1=f 2=g 3=o
      const float* wp = whh + ((size_t)dir * 2048 + q * 512 + j0 + r) * 512 + kg;
      #pragma unroll
      for (int kt = 0; kt < 16; ++kt) {
        float4 v0 = *(const float4*)(wp + kt * 32);
        float4 v1 = *(const float4*)(wp + kt * 32 + 4);
        union { u16 u[8]; bf16x8 v; } t;
        t.u[0] = f2bf(v0.x); t.u[1] = f2bf(v0.y); t.u[2] = f2bf(v0.z); t.u[3] = f2bf(v0.w);
        t.u[4] = f2bf(v1.x); t.u[5] = f2bf(v1.y); t.u[6] = f2bf(v1.z); t.u[7] = f2bf(v1.w);
        bw[nt][kt] = t.v;
      }
    }
  }

  const int eb = tid >> 3;          // batch row handled in elementwise
  const int pr = (tid & 7) * 2;     // h-col pair within chunk
  float c0 = 0.f, c1 = 0.f;

  for (int s = 0; s < 512; ++s) {
    const int cur = s & 1, nxt = cur ^ 1;
    const int tcur = dir ? (511 - s) : s;

    // prefetch gx (i,f,g,o for this thread's two columns)
    const u16* gxr = gx + ((size_t)(dir * 512 + tcur) * 32 + eb) * 2048 + j0;
    uint32_t gq[4];
    #pragma unroll
    for (int q = 0; q < 4; ++q) gq[q] = *(const uint32_t*)(gxr + q * 512 + pr);

    // A fragments from previous h
    const u16* ap = hbuf + ((size_t)(dir * 2 + cur) * 32 + mh * 16 + (lane & 15)) * 512 + (lane >> 4) * 8;
    bf16x8 af[16];
    #pragma unroll
    for (int kt = 0; kt < 16; ++kt) af[kt] = *(const bf16x8*)(ap + kt * 32);

    f32x4 acc0 = {0.f, 0.f, 0.f, 0.f}, acc1 = {0.f, 0.f, 0.f, 0.f};
    #pragma unroll
    for (int kt = 0; kt < 16; ++kt) {
      acc0 = __builtin_amdgcn_mfma_f32_16x16x32_bf16(af[kt], bw[0][kt], acc0, 0, 0, 0);
      acc1 = __builtin_amdgcn_mfma_f32_16x16x32_bf16(af[kt], bw[1][kt], acc1, 0, 0, 0);
    }
    #pragma unroll
    for (int r = 0; r < 4; ++r) {
      G[mh * 16 + (lane >> 4) * 4 + r][nh * 32 + (lane & 15)]      = acc0[r];
      G[mh * 16 + (lane >> 4) * 4 + r][nh * 32 + 16 + (lane & 15)] = acc1[r];
    }
    __syncthreads();

    // elementwise LSTM cell for (eb, j0+pr) and (eb, j0+pr+1)
    {
      float i0 = G[eb][pr]      + bf2f((u16)(gq[0] & 0xFFFF));
      float i1 = G[eb][pr + 1]  + bf2f((u16)(gq[0] >> 16));
      float f0 = G[eb][pr + 16] + bf2f((u16)(gq[1] & 0xFFFF));
      float f1 = G[eb][pr + 17] + bf2f((u16)(gq[1] >> 16));
      float g0 = G[eb][pr + 32] + bf2f((u16)(gq[2] & 0xFFFF));
      float g1 = G[eb][pr + 33] + bf2f((u16)(gq[2] >> 16));
      float o0 = G[eb][pr + 48] + bf2f((u16)(gq[3] & 0xFFFF));
      float o1 = G[eb][pr + 49] + bf2f((u16)(gq[3] >> 16));
      c0 = sigf(f0) * c0 + sigf(i0) * tanhf_(g0);
      c1 = sigf(f1) * c1 + sigf(i1) * tanhf_(g1);
      float h0 = sigf(o0) * tanhf_(c0);
      float h1 = sigf(o1) * tanhf_(c1);
      uint32_t hp = (uint32_t)f2bf(h0) | ((uint32_t)f2bf(h1) << 16);
      *(uint32_t*)(hbuf + ((size_t)(dir * 2 + nxt) * 32 + eb) * 512 + j0 + pr) = hp;
      *(uint32_t*)(xout + ((size_t)eb * 512 + tcur) * 1024 + dir * 512 + j0 + pr) = hp;
    }

    __syncthreads();   // all waves drained (vmcnt(0) before s_barrier)
    if (tid == 0) {
      __builtin_amdgcn_fence(__ATOMIC_RELEASE, "agent");
      __hip_atomic_fetch_add(ctr, 1u, __ATOMIC_RELAXED, __HIP_MEMORY_SCOPE_AGENT);
      const unsigned tgt = (unsigned)(s + 1) * 32u;
      while (__hip_atomic_load(ctr, __ATOMIC_RELAXED, __HIP_MEMORY_SCOPE_AGENT) < tgt)
        __builtin_amdgcn_s_sleep(8);
      __builtin_amdgcn_fence(__ATOMIC_ACQUIRE, "agent");
    }
    __syncthreads();
  }
}

// ---------------- classifier stage 1: h1[b][j] = tanh(dot(w1[j], hidden[b]) + b1[j]) ----------------
__global__ void k_cls1(const u16* __restrict__ x3, const int* __restrict__ idxb,
                       const float* __restrict__ w1, const float* __restrict__ b1,
                       float* __restrict__ h1) {
  __shared__ u16 hid[32][1024];
  const int tid = threadIdx.x;
  for (int g = tid; g < 4096; g += 256) {
    const int b = g >> 7;
    const int c8 = (g & 127) * 8;
    *(uint4*)&hid[b][c8] = *(const uint4*)(x3 + ((size_t)b * 512 + idxb[b]) * 1024 + c8);
  }
  __syncthreads();
  for (int p = tid; p < 1024; p += 256) {
    const int j = blockIdx.x * 32 + (p >> 5);
    const int b = p & 31;
    const float4* wr = (const float4*)(w1 + (size_t)j * 1024);
    float s = 0.f;
    for (int k4 = 0; k4 < 256; ++k4) {
      float4 wv = wr[k4];
      const int k = k4 * 4;
      s += bf2f(hid[b][k]) * wv.x + bf2f(hid[b][k + 1]) * wv.y
         + bf2f(hid[b][k + 2]) * wv.z + bf2f(hid[b][k + 3]) * wv.w;
    }
    h1[b * 512 + j] = tanhf_(s + b1[j]);
  }
}

// ---------------- classifier stage 2: BCE-with-logits mean ----------------
__global__ void k_cls2(const float* __restrict__ h1, const float* __restrict__ w2,
                       const float* __restrict__ b2, const float* __restrict__ label,
                       float* __restrict__ out) {
  const int lane = threadIdx.x;   // 64
  float loss = 0.f;
  for (int b = 0; b < 32; ++b) {
    float s = 0.f;
    for (int k = lane; k < 512; k += 64) s += h1[b * 512 + k] * w2[k];
    for (int off = 32; off; off >>= 1) s += __shfl_down(s, off);
    if (lane == 0) {
      const float z = s + b2[0];
      const float y = label[b];
      const float sp = fmaxf(z, 0.f) + log1pf(__expf(-fabsf(z)));
      loss += sp - z * y;
    }
  }
  if (lane == 0) out[0] = loss / 32.0f;
}

extern "C" void kernel_launch(void* const* d_in, const int* in_sizes, int n_in,
                              void* d_out, int out_size, void* d_ws, size_t ws_size,
                              hipStream_t stream) {
  const int*   seq   = (const int*)  d_in[0];
  const float* label = (const float*)d_in[1];
  const float* wemb  = (const float*)d_in[2];
  const float* wih   = (const float*)d_in[3];
  const float* whh   = (const float*)d_in[4];
  const float* bb    = (const float*)d_in[5];
  const float* w1    = (const float*)d_in[6];
  const float* b1    = (const float*)d_in[7];
  const float* w2    = (const float*)d_in[8];
  const float* b2    = (const float*)d_in[9];

  u16* x1   = (u16*)d_ws;                       // [32][512][1024] bf16   (layer1 in, reused as layer2 out)
  u16* x2   = x1 + (size_t)16777216;            // [32][512][1024] bf16   (layer1 out / layer2 in)
  u16* gxb  = x2 + (size_t)16777216;            // [2][512][32][2048] bf16
  u16* wb   = gxb + (size_t)67108864;           // [4096][1024] bf16
  float* h1 = (float*)(wb + 4194304);           // [32][512] f32
  int* idxb = (int*)(h1 + 16384);               // [32]
  u16* hbuf = (u16*)(idxb + 32);                // [2][2][32][512] bf16
  unsigned* ctr = (unsigned*)(hbuf + 65536);    // counters

  // layer 1
  hipMemsetAsync(hbuf, 0, 131072 + 256, stream);
  k_emb<<<16384, 256, 0, stream>>>(seq, wemb, x1);
  k_idx<<<1, 256, 0, stream>>>(seq, idxb);
  k_cast<<<4096, 256, 0, stream>>>(wih, wb);
  k_gemm<<<dim3(128, 32), 256, 0, stream>>>(x1, wb, bb, gxb);
  k_rec<<<64, 256, 0, stream>>>(gxb, whh, x2, hbuf, ctr);
  // layer 2
  hipMemsetAsync(hbuf, 0, 131072 + 256, stream);
  k_cast<<<4096, 256, 0, stream>>>(wih + 4194304, wb);
  k_gemm<<<dim3(128, 32), 256, 0, stream>>>(x2, wb, bb + 4096, gxb);
  k_rec<<<64, 256, 0, stream>>>(gxb, whh + 2097152, x1, hbuf, ctr);
  // head
  k_cls1<<<16, 256, 0, stream>>>(x1, idxb, w1, b1, h1);
  k_cls2<<<1, 64, 0, stream>>>(h1, w2, b2, label, (float*)d_out);
}

// Round 2
// 4906.250 us; speedup vs baseline: 1.5827x; 1.5827x over previous
//
#include <hip/hip_runtime.h>
#include <stdint.h>

typedef unsigned short u16;
typedef __bf16 bf16x8 __attribute__((ext_vector_type(8)));
typedef float  f32x4  __attribute__((ext_vector_type(4)));

#define GPTR(p) ((const __attribute__((address_space(1))) void*)(p))
#define LPTR(p) ((__attribute__((address_space(3))) void*)(p))

__device__ __forceinline__ u16 f2bf(float f) {
  uint32_t u = __float_as_uint(f);
  u += 0x7FFFu + ((u >> 16) & 1u);
  return (u16)(u >> 16);
}
__device__ __forceinline__ float bf2f(u16 h) {
  return __uint_as_float(((uint32_t)h) << 16);
}
__device__ __forceinline__ float sigf(float x) { return 1.0f / (1.0f + __expf(-x)); }
__device__ __forceinline__ float tanhf_(float x) { return 1.0f - 2.0f / (__expf(2.0f * x) + 1.0f); }

// ---------------- embedding gather ----------------
__global__ void k_emb(const int* __restrict__ seq, const float* __restrict__ wemb,
                      u16* __restrict__ x1) {
  const int row = blockIdx.x;          // 0..16383
  const int tok = seq[row];
  float4 v = ((const float4*)(wemb + (size_t)tok * 1024))[threadIdx.x];
  uint32_t lo = (uint32_t)f2bf(v.x) | ((uint32_t)f2bf(v.y) << 16);
  uint32_t hi = (uint32_t)f2bf(v.z) | ((uint32_t)f2bf(v.w) << 16);
  *(uint2*)(x1 + (size_t)row * 1024 + threadIdx.x * 4) = make_uint2(lo, hi);
}

// ---------------- marker index per row ----------------
__global__ void k_idx(const int* __restrict__ seq, int* __restrict__ idxb) {
  const int tid = threadIdx.x;         // 256
  const int b = tid >> 3, part = tid & 7;
  for (int t = part * 64; t < part * 64 + 64; ++t)
    if (seq[b * 512 + t] == 50000) idxb[b] = t;
}

// ---------------- cast 4096x1024 f32 -> bf16 ----------------
__global__ void k_cast(const float* __restrict__ src, u16* __restrict__ dst) {
  const int i = blockIdx.x * 256 + threadIdx.x;
  float4 v = ((const float4*)src)[i];
  uint32_t lo = (uint32_t)f2bf(v.x) | ((uint32_t)f2bf(v.y) << 16);
  uint32_t hi = (uint32_t)f2bf(v.z) | ((uint32_t)f2bf(v.w) << 16);
  *(uint2*)(dst + (size_t)i * 4) = make_uint2(lo, hi);
}

// ---------------- GEMM: gx[d][t][b][(j>>4)*64 + q*16 + (j&15)] ----------------
__global__ __launch_bounds__(256) void k_gemm(
    const u16* __restrict__ X, const u16* __restrict__ W,
    const float* __restrict__ bias, u16* __restrict__ gx)
{
  __shared__ u16 As[128][32];
  __shared__ u16 Bs[128][32];
  const int tid = threadIdx.x;
  const int lane = tid & 63;
  const int wv = tid >> 6;
  const int wm = wv >> 1, wn = wv & 1;
  const int bm = blockIdx.x, bn = blockIdx.y;
  const int srow = tid >> 2;
  const int scg = (tid & 3) * 8;
  const u16* Xb = X + (size_t)bm * 128 * 1024;
  const u16* Wb = W + (size_t)bn * 128 * 1024;
  f32x4 acc[4][4] = {};
  for (int k0 = 0; k0 < 1024; k0 += 32) {
    __builtin_amdgcn_global_load_lds(GPTR(Xb + (size_t)srow * 1024 + k0 + scg),        LPTR(&As[srow][scg]),       16, 0, 0);
    __builtin_amdgcn_global_load_lds(GPTR(Xb + (size_t)(srow + 64) * 1024 + k0 + scg), LPTR(&As[srow + 64][scg]), 16, 0, 0);
    __builtin_amdgcn_global_load_lds(GPTR(Wb + (size_t)srow * 1024 + k0 + scg),        LPTR(&Bs[srow][scg]),       16, 0, 0);
    __builtin_amdgcn_global_load_lds(GPTR(Wb + (size_t)(srow + 64) * 1024 + k0 + scg), LPTR(&Bs[srow + 64][scg]), 16, 0, 0);
    __syncthreads();
    const int kg = (lane >> 4) * 8;
    bf16x8 a4[4], b4[4];
    #pragma unroll
    for (int mt = 0; mt < 4; ++mt) a4[mt] = *(const bf16x8*)&As[wm * 64 + mt * 16 + (lane & 15)][kg];
    #pragma unroll
    for (int nt = 0; nt < 4; ++nt) b4[nt] = *(const bf16x8*)&Bs[wn * 64 + nt * 16 + (lane & 15)][kg];
    #pragma unroll
    for (int mt = 0; mt < 4; ++mt)
      #pragma unroll
      for (int nt = 0; nt < 4; ++nt)
        acc[mt][nt] = __builtin_amdgcn_mfma_f32_16x16x32_bf16(a4[mt], b4[nt], acc[mt][nt], 0, 0, 0);
    __syncthreads();
  }
  #pragma unroll
  for (int mt = 0; mt < 4; ++mt) {
    const int mbase = bm * 128 + wm * 64 + mt * 16 + ((lane >> 4) << 2);
    #pragma unroll
    for (int nt = 0; nt < 4; ++nt) {
      const int n = bn * 128 + wn * 64 + nt * 16 + (lane & 15);
      const float bi = bias[n];
      const int d = n >> 11;
      const int nn = n & 2047;
      const int q = nn >> 9;          // gate
      const int j = nn & 511;         // h column
      const int col = (j >> 4) * 64 + q * 16 + (j & 15);
      #pragma unroll
      for (int r = 0; r < 4; ++r) {
        const int mm = mbase + r;
        const int b = mm >> 9, t = mm & 511;
        gx[((size_t)(d * 512 + t) * 32 + b) * 2048 + col] = f2bf(acc[mt][nt][r] + bi);
      }
    }
  }
}

// ---------------- persistent bidirectional recurrence ----------------
// 64 blocks: dir = bid>>5, db = bid&31 owns h-cols [db*16, db*16+16).
// h + per-block step-stamps exchanged via sc0/sc1 (device-coherent, LLC) loads/stores.
// No fences, no atomic RMW, no L2 invalidation.
__global__ __launch_bounds__(256, 1) void k_rec(
    const u16* __restrict__ gx, const float* __restrict__ whh,
    u16* __restrict__ xout, u16* hbuf, unsigned* ctrbase)
{
  const int bid = blockIdx.x;
  const int dir = bid >> 5;
  const int db = bid & 31;
  const int j0 = db * 16;
  const int tid = threadIdx.x;
  const int lane = tid & 63;
  const int wv = tid >> 6;
  const int mh = wv >> 1, nh = wv & 1;
  unsigned* flags = ctrbase + dir * 32;

  __shared__ float G[32][69];

  // ---- Whh chunk -> registers (bf16 B-fragments)
  bf16x8 bw[2][16];
  {
    const int r = lane & 15;
    const int kg = (lane >> 4) * 8;
    #pragma unroll
    for (int nt = 0; nt < 2; ++nt) {
      const int q = nh * 2 + nt;   // gate: 0=i 1=f 2=g 3=o
      const float* wp = whh + ((size_t)dir * 2048 + q * 512 + j0 + r) * 512 + kg;
      #pragma unroll
      for (int kt = 0; kt < 16; ++kt) {
        float4 v0 = *(const float4*)(wp + kt * 32);
        float4 v1 = *(const float4*)(wp + kt * 32 + 4);
        union { u16 u[8]; bf16x8 v; } t;
        t.u[0] = f2bf(v0.x); t.u[1] = f2bf(v0.y); t.u[2] = f2bf(v0.z); t.u[3] = f2bf(v0.w);
        t.u[4] = f2bf(v1.x); t.u[5] = f2bf(v1.y); t.u[6] = f2bf(v1.z); t.u[7] = f2bf(v1.w);
        bw[nt][kt] = t.v;
      }
    }
  }

  const int eb = tid >> 3;          // batch row for elementwise
  const int pr = (tid & 7) * 2;     // h-col pair within chunk
  float c0 = 0.f, c1 = 0.f;

  const u16* apbase = hbuf + ((size_t)(dir * 2) * 32 + mh * 16 + (lane & 15)) * 512 + (lane >> 4) * 8;

  for (int s = 0; s < 512; ++s) {
    const int cur = s & 1, nxt = cur ^ 1;
    const int tcur = dir ? (511 - s) : s;

    // ---- wait: all 32 blocks of this direction have published h(s-1)
    if (s) {
      const unsigned tgt = (unsigned)s;
      const unsigned* fp = flags + (lane & 31);
      while (true) {
        unsigned fv;
        asm volatile("global_load_dword %0, %1, off sc0 sc1\n\ts_waitcnt vmcnt(0)"
                     : "=v"(fv) : "v"(fp) : "memory");
        if (__all((int)(fv >= tgt))) break;
      }
      __builtin_amdgcn_sched_barrier(0);
    }

    // ---- issue 16 coherent h-fragment loads (A fragments), then 4 gx loads
    uint4 afu[16];
    const u16* ap = apbase + (size_t)cur * 16384;
    #pragma unroll
    for (int kt = 0; kt < 16; ++kt)
      asm volatile("global_load_dwordx4 %0, %1, off sc0 sc1"
                   : "=v"(afu[kt]) : "v"(ap + kt * 32) : "memory");
    uint32_t gq[4];
    const u16* gxr = gx + ((size_t)(dir * 512 + tcur) * 32 + eb) * 2048 + db * 64 + pr;
    #pragma unroll
    for (int q = 0; q < 4; ++q)
      asm volatile("global_load_dword %0, %1, off"
                   : "=v"(gq[q]) : "v"(gxr + q * 16) : "memory");

    // ---- MFMA chain overlapped with load completion (manual vmcnt: 16 af + 4 gq in order)
    f32x4 acc0 = {0.f, 0.f, 0.f, 0.f}, acc1 = {0.f, 0.f, 0.f, 0.f};
    asm volatile("s_waitcnt vmcnt(12)" ::: "memory");   // af[0..7] done
    __builtin_amdgcn_sched_barrier(0);
    #pragma unroll
    for (int kt = 0; kt < 8; ++kt) {
      bf16x8 a = __builtin_bit_cast(bf16x8, afu[kt]);
      acc0 = __builtin_amdgcn_mfma_f32_16x16x32_bf16(a, bw[0][kt], acc0, 0, 0, 0);
      acc1 = __builtin_amdgcn_mfma_f32_16x16x32_bf16(a, bw[1][kt], acc1, 0, 0, 0);
    }
    asm volatile("s_waitcnt vmcnt(4)" ::: "memory");    // af[8..15] done
    __builtin_amdgcn_sched_barrier(0);
    #pragma unroll
    for (int kt = 8; kt < 16; ++kt) {
      bf16x8 a = __builtin_bit_cast(bf16x8, afu[kt]);
      acc0 = __builtin_amdgcn_mfma_f32_16x16x32_bf16(a, bw[0][kt], acc0, 0, 0, 0);
      acc1 = __builtin_amdgcn_mfma_f32_16x16x32_bf16(a, bw[1][kt], acc1, 0, 0, 0);
    }

    #pragma unroll
    for (int r = 0; r < 4; ++r) {
      G[mh * 16 + (lane >> 4) * 4 + r][nh * 32 + (lane & 15)]      = acc0[r];
      G[mh * 16 + (lane >> 4) * 4 + r][nh * 32 + 16 + (lane & 15)] = acc1[r];
    }
    asm volatile("s_waitcnt vmcnt(0)" ::: "memory");    // gq done
    __syncthreads();

    // ---- elementwise LSTM cell for (eb, j0+pr) and (eb, j0+pr+1)
    {
      float i0 = G[eb][pr]      + bf2f((u16)(gq[0] & 0xFFFF));
      float i1 = G[eb][pr + 1]  + bf2f((u16)(gq[0] >> 16));
      float f0 = G[eb][pr + 16] + bf2f((u16)(gq[1] & 0xFFFF));
      float f1 = G[eb][pr + 17] + bf2f((u16)(gq[1] >> 16));
      float g0 = G[eb][pr + 32] + bf2f((u16)(gq[2] & 0xFFFF));
      float g1 = G[eb][pr + 33] + bf2f((u16)(gq[2] >> 16));
      float o0 = G[eb][pr + 48] + bf2f((u16)(gq[3] & 0xFFFF));
      float o1 = G[eb][pr + 49] + bf2f((u16)(gq[3] >> 16));
      c0 = sigf(f0) * c0 + sigf(i0) * tanhf_(g0);
      c1 = sigf(f1) * c1 + sigf(i1) * tanhf_(g1);
      float h0 = sigf(o0) * tanhf_(c0);
      float h1 = sigf(o1) * tanhf_(c1);
      uint32_t hp = (uint32_t)f2bf(h0) | ((uint32_t)f2bf(h1) << 16);
      u16* hdst = hbuf + ((size_t)(dir * 2 + nxt) * 32 + eb) * 512 + j0 + pr;
      asm volatile("global_store_dword %0, %1, off sc0 sc1"
                   :: "v"(hdst), "v"(hp) : "memory");
      *(uint32_t*)(xout + ((size_t)eb * 512 + tcur) * 1024 + dir * 512 + j0 + pr) = hp;
    }

    asm volatile("s_waitcnt vmcnt(0)" ::: "memory");    // h + xout stores globally visible
    __syncthreads();                                     // whole block done storing
    if (tid == 0) {
      unsigned fv = (unsigned)(s + 1);
      asm volatile("global_store_dword %0, %1, off sc0 sc1"
                   :: "v"(flags + db), "v"(fv) : "memory");
    }
  }
}

// ---------------- classifier stage 1 ----------------
__global__ void k_cls1(const u16* __restrict__ x3, const int* __restrict__ idxb,
                       const float* __restrict__ w1, const float* __restrict__ b1,
                       float* __restrict__ h1) {
  __shared__ u16 hid[32][1024];
  const int tid = threadIdx.x;
  for (int g = tid; g < 4096; g += 256) {
    const int b = g >> 7;
    const int c8 = (g & 127) * 8;
    *(uint4*)&hid[b][c8] = *(const uint4*)(x3 + ((size_t)b * 512 + idxb[b]) * 1024 + c8);
  }
  __syncthreads();
  for (int p = tid; p < 1024; p += 256) {
    const int j = blockIdx.x * 32 + (p >> 5);
    const int b = p & 31;
    const float4* wr = (const float4*)(w1 + (size_t)j * 1024);
    float s = 0.f;
    for (int k4 = 0; k4 < 256; ++k4) {
      float4 wv = wr[k4];
      const int k = k4 * 4;
      s += bf2f(hid[b][k]) * wv.x + bf2f(hid[b][k + 1]) * wv.y
         + bf2f(hid[b][k + 2]) * wv.z + bf2f(hid[b][k + 3]) * wv.w;
    }
    h1[b * 512 + j] = tanhf_(s + b1[j]);
  }
}

// ---------------- classifier stage 2: BCE-with-logits mean ----------------
__global__ void k_cls2(const float* __restrict__ h1, const float* __restrict__ w2,
                       const float* __restrict__ b2, const float* __restrict__ label,
                       float* __restrict__ out) {
  const int lane = threadIdx.x;   // 64
  float loss = 0.f;
  for (int b = 0; b < 32; ++b) {
    float s = 0.f;
    for (int k = lane; k < 512; k += 64) s += h1[b * 512 + k] * w2[k];
    for (int off = 32; off; off >>= 1) s += __shfl_down(s, off);
    if (lane == 0) {
      const float z = s + b2[0];
      const float y = label[b];
      const float sp = fmaxf(z, 0.f) + log1pf(__expf(-fabsf(z)));
      loss += sp - z * y;
    }
  }
  if (lane == 0) out[0] = loss / 32.0f;
}

extern "C" void kernel_launch(void* const* d_in, const int* in_sizes, int n_in,
                              void* d_out, int out_size, void* d_ws, size_t ws_size,
                              hipStream_t stream) {
  const int*   seq   = (const int*)  d_in[0];
  const float* label = (const float*)d_in[1];
  const float* wemb  = (const float*)d_in[2];
  const float* wih   = (const float*)d_in[3];
  const float* whh   = (const float*)d_in[4];
  const float* bb    = (const float*)d_in[5];
  const float* w1    = (const float*)d_in[6];
  const float* b1    = (const float*)d_in[7];
  const float* w2    = (const float*)d_in[8];
  const float* b2    = (const float*)d_in[9];

  u16* x1   = (u16*)d_ws;                       // [32][512][1024] bf16
  u16* x2   = x1 + (size_t)16777216;            // [32][512][1024] bf16
  u16* gxb  = x2 + (size_t)16777216;            // [2][512][32][2048] bf16
  u16* wb   = gxb + (size_t)67108864;           // [4096][1024] bf16
  float* h1 = (float*)(wb + 4194304);           // [32][512] f32
  int* idxb = (int*)(h1 + 16384);               // [32]
  u16* hbuf = (u16*)(idxb + 32);                // [2][2][32][512] bf16
  unsigned* ctr = (unsigned*)(hbuf + 65536);    // 64 step-stamps

  // layer 1
  hipMemsetAsync(hbuf, 0, 131072 + 256, stream);
  k_emb<<<16384, 256, 0, stream>>>(seq, wemb, x1);
  k_idx<<<1, 256, 0, stream>>>(seq, idxb);
  k_cast<<<4096, 256, 0, stream>>>(wih, wb);
  k_gemm<<<dim3(128, 32), 256, 0, stream>>>(x1, wb, bb, gxb);
  k_rec<<<64, 256, 0, stream>>>(gxb, whh, x2, hbuf, ctr);
  // layer 2
  hipMemsetAsync(hbuf, 0, 131072 + 256, stream);
  k_cast<<<4096, 256, 0, stream>>>(wih + 4194304, wb);
  k_gemm<<<dim3(128, 32), 256, 0, stream>>>(x2, wb, bb + 4096, gxb);
  k_rec<<<64, 256, 0, stream>>>(gxb, whh + 2097152, x1, hbuf, ctr);
  // head
  k_cls1<<<16, 256, 0, stream>>>(x1, idxb, w1, b1, h1);
  k_cls2<<<1, 64, 0, stream>>>(h1, w2, b2, label, (float*)d_out);
}